// Round 12
// baseline (282.352 us; speedup 1.0000x reference)
//
#include <hip/hip_runtime.h>

// DeformConv fused pipeline, MI355X gfx950. Shapes: B=2, Ci=Co=256, H=W=96.
// R12 changes vs R11 (depth-3 pipeline SPILLED: VGPR=128 cap + 200MB scratch
// writes -> 163us regression):
//  - sample_s: depth-2 pinned pipeline, 256-thr blocks, launch_bounds(256,3)
//    (VGPR cap 170), incremental group stores free pkw regs (~10 live not 36).
//    Expect VGPR ~150, WRITE_SIZE ~83MB (observables).

typedef unsigned short ushort_t;
typedef unsigned int uint_t;
typedef __attribute__((ext_vector_type(8))) short bf16x8;
typedef __attribute__((ext_vector_type(4))) float f32x4;
typedef __attribute__((ext_vector_type(2), aligned(4))) float f32x2a;

#define HH 96
#define WW 96
#define HWSZ 9216
#define CI 256
#define CO 256
#define NB 2
#define NPIX 18432
#define KTOT 2304

__device__ __forceinline__ ushort_t f2bf(float f) {
  unsigned int u = __float_as_uint(f);
  u += 0x7fffu + ((u >> 16) & 1u);
  return (ushort_t)(u >> 16);
}
__device__ __forceinline__ float u2f(uint_t u) { return __uint_as_float(u); }

__device__ __forceinline__ void gload16(const void* g, void* l) {
  __builtin_amdgcn_global_load_lds(
      (const __attribute__((address_space(1))) unsigned int*)g,
      (__attribute__((address_space(3))) unsigned int*)l, 16, 0, 0);
}

// ---------------- cvt_w9: w_dcn -> bf16 [kk>>3][m][kk&7] ----------------
__global__ void cvt_w9(const float* __restrict__ w, ushort_t* __restrict__ o) {
  int i = blockIdx.x * 256 + threadIdx.x;      // grid exact CO*KTOT
  int oo = i / KTOT;
  int kk = i - oo * KTOT;
  o[(kk >> 3) * 2048 + oo * 8 + (kk & 7)] = f2bf(w[i]);
}

// ---------------- cvt_woff9: w_off -> bf16 [kk>>3][m32][kk&7], rows>=27 zero ----
__global__ void cvt_woff9(const float* __restrict__ w, ushort_t* __restrict__ o) {
  int i = blockIdx.x * 256 + threadIdx.x;      // grid exact 32*KTOT
  int m = i / KTOT;
  int kk = i - m * KTOT;
  float v = (m < 27) ? w[m * KTOT + kk] : 0.f;
  o[(kk >> 3) * 256 + m * 8 + (kk & 7)] = f2bf(v);
}

// ---------------- off_gemm: om_part[part][27][NPIX], K-split halves ----------------
__global__ __launch_bounds__(512, 2) void off_gemm(
    const float* __restrict__ x, const ushort_t* __restrict__ w27r,
    float* __restrict__ om_part) {
  __shared__ __align__(16) ushort_t A27[2][2048];
  __shared__ __align__(16) ushort_t B64[4096];
  __shared__ uint2 tbl[9][64];                 // {abs idx (0 if invalid), mask}

  const int tid = threadIdx.x;
  const int lane = tid & 63, wid = tid >> 6;
  const int p0 = blockIdx.x * 64;
  const int part = blockIdx.y;                 // K half
  const int bimg = p0 / HWSZ;
  const int hw0 = p0 - bimg * HWSZ;
  const float* xb = x + (size_t)bimg * CI * HWSZ;

  for (int e = tid; e < 576; e += 512) {
    int k = e >> 6, px = e & 63;
    int hw = hw0 + px, h = hw / WW, w_ = hw - h * WW;
    int dy = k / 3 - 1, dx = k % 3 - 1;
    bool ok = (h + dy >= 0) && (h + dy < HH) && (w_ + dx >= 0) && (w_ + dx < WW);
    tbl[k][px] = make_uint2(ok ? (uint_t)(hw + dy * WW + dx) : 0u,
                            ok ? 0x3f800000u : 0u);
  }

  const int lg = lane >> 4, lm = lane & 15;
  const int wr = wid >> 2, wc = wid & 3;
  f32x4 acc = (f32x4){0.f, 0.f, 0.f, 0.f};

  int cj[8], kj[8];
#pragma unroll
  for (int j = 0; j < 8; ++j) {
    int kk = part * 1152 + wid * 8 + j;
    cj[j] = kk / 9;
    kj[j] = kk - 9 * cj[j];
  }
  __syncthreads();

  float rv0[8], rm0[8], rv1[8], rm1[8];
  const int k0 = part * 18;

#define OG_RAW(RV, RM)                                                        \
  { _Pragma("unroll") for (int j = 0; j < 8; ++j) {                           \
      uint2 e_ = tbl[kj[j]][lane];                                            \
      RV[j] = xb[cj[j] * HWSZ + (int)e_.x];                                   \
      RM[j] = u2f(e_.y);                                                      \
      kj[j] += 1; cj[j] += 7;                                                 \
      if (kj[j] == 9) { kj[j] = 0; cj[j] += 1; } } }
#define OG_GA(CH, BUF)                                                        \
  gload16(w27r + (size_t)(CH) * 2048 + (tid & 255) * 8, &A27[BUF][(wid & 3) * 512]);
#define OG_STEP(CUR, RVC, RMC, RVN, RMN, KO)                                  \
  {                                                                           \
    if ((KO) < 17) {                                                          \
      OG_RAW(RVN, RMN)                                                        \
      OG_GA(k0 + (KO) + 1, (CUR) ^ 1)                                         \
      asm volatile("s_waitcnt vmcnt(10)" ::: "memory");                       \
    } else {                                                                  \
      asm volatile("s_waitcnt vmcnt(1)" ::: "memory");                        \
    }                                                                         \
    __builtin_amdgcn_sched_barrier(0);                                        \
    {                                                                         \
      ushort_t sv_[8] __attribute__((aligned(16)));                           \
      _Pragma("unroll") for (int j = 0; j < 8; ++j)                           \
        sv_[j] = f2bf(RVC[j] * RMC[j]);                                       \
      *(uint4*)&B64[tid * 8] = *(const uint4*)sv_;                            \
    }                                                                         \
    if ((KO) < 17) asm volatile("s_waitcnt vmcnt(9) lgkmcnt(0)" ::: "memory"); \
    else           asm volatile("s_waitcnt vmcnt(0) lgkmcnt(0)" ::: "memory"); \
    __builtin_amdgcn_s_barrier();                                             \
    __builtin_amdgcn_sched_barrier(0);                                        \
    _Pragma("unroll") for (int s = 0; s < 2; ++s) {                           \
      bf16x8 af = *(const bf16x8*)&A27[CUR][((s * 4 + lg) * 32 + wr * 16 + lm) * 8]; \
      bf16x8 bfv = *(const bf16x8*)&B64[((s * 4 + lg) * 64 + wc * 16 + lm) * 8];     \
      acc = __builtin_amdgcn_mfma_f32_16x16x32_bf16(af, bfv, acc, 0, 0, 0);   \
    }                                                                         \
    asm volatile("s_waitcnt lgkmcnt(0)" ::: "memory");                        \
    __builtin_amdgcn_s_barrier();                                             \
    __builtin_amdgcn_sched_barrier(0);                                        \
  }

  OG_RAW(rv0, rm0)
  OG_GA(k0, 0)
  for (int ko2 = 0; ko2 < 9; ++ko2) {
    const int ko = ko2 * 2;
    OG_STEP(0, rv0, rm0, rv1, rm1, ko)
    OG_STEP(1, rv1, rm1, rv0, rm0, ko + 1)
  }
#undef OG_RAW
#undef OG_GA
#undef OG_STEP

  int row = wr * 16 + lg * 4;
  int col = p0 + wc * 16 + lm;
#pragma unroll
  for (int r = 0; r < 4; ++r)
    if (row + r < 27)
      om_part[((size_t)(part * 27 + row + r)) * NPIX + col] = acc[r];
}

// ---------------- prep: sum om halves -> row-pair offsets + folded weights ----------------
__global__ void prep_kernel(const float* __restrict__ om_part, const float* __restrict__ b_off,
                            uint_t* __restrict__ offs, float4* __restrict__ wts) {
  int n = blockIdx.x * 128 + threadIdx.x;      // grid 144 x 128
  float omv[27];
#pragma unroll
  for (int ch = 0; ch < 27; ++ch)
    omv[ch] = b_off[ch] + om_part[(size_t)ch * NPIX + n] +
              om_part[((size_t)(27 + ch)) * NPIX + n];
  int hw = n % HWSZ;
  int h = hw / WW, w = hw - h * WW;
#pragma unroll
  for (int k = 0; k < 9; ++k) {
    float dy = omv[2 * k], dx = omv[2 * k + 1];
    float mk = 1.f / (1.f + __expf(-omv[18 + k]));
    float py = dy + (float)(h - 1 + k / 3);
    float px = dx + (float)(w - 1 + k % 3);
    float y0f = floorf(py), x0f = floorf(px);
    int y0 = (int)y0f, x0 = (int)x0f;
    float wy1 = py - y0f, wx1 = px - x0f;
    float wy0 = 1.f - wy1, wx0 = 1.f - wx1;
    float vy0 = (y0 >= 0 && y0 <= HH - 1) ? 1.f : 0.f;
    float vy1 = (y0 + 1 >= 0 && y0 + 1 <= HH - 1) ? 1.f : 0.f;
    int yc0 = min(max(y0, 0), HH - 1), yc1 = min(max(y0 + 1, 0), HH - 1);
    int xa = min(max(x0, 0), WW - 2);
    float a_, b_;
    if (x0 >= 0 && x0 <= WW - 2)      { a_ = wx0; b_ = wx1; }
    else if (x0 == -1)                { a_ = wx1; b_ = 0.f; }
    else if (x0 == WW - 1)            { a_ = 0.f; b_ = wx0; }
    else                              { a_ = 0.f; b_ = 0.f; }
    float s0 = mk * vy0 * wy0, s1 = mk * vy1 * wy1;
    offs[(size_t)k * NPIX + n] = (uint_t)(yc0 * WW + xa) | ((uint_t)(yc1 * WW + xa) << 16);
    wts[(size_t)k * NPIX + n] = make_float4(a_ * s0, b_ * s0, a_ * s1, b_ * s1);
  }
}

// ---------------- sample_s: S_g[kk>>3][n][kk&7] bf16, c-major kk ----------------
// Grid 288 x 8; 256 thr (4 waves), wave = 8 channels, c-inner taps (L1 reuse).
// Depth-2 named-reg pipeline pinned with sched_barrier(0); groups stored as
// soon as complete (g0..g8 after ch0..ch7) so pkw stays ~10 live regs.
__global__ __launch_bounds__(256, 3) void sample_s(
    const float* __restrict__ x, const uint_t* __restrict__ offs,
    const float4* __restrict__ wts, ushort_t* __restrict__ S_g) {
  const int tid = threadIdx.x;
  const int lane = tid & 63, wid = tid >> 6;   // 4 waves
  const int p0 = blockIdx.x * 64;
  const int part = blockIdx.y;                 // 0..7
  const int n = p0 + lane;
  const int bimg = p0 / HWSZ;
  const int c8 = part * 32 + wid * 8;
  const float* xc0 = x + ((size_t)bimg * CI + c8) * HWSZ;

  uint_t ofr[9]; float4 wtr[9];
#pragma unroll
  for (int k = 0; k < 9; ++k) {
    ofr[k] = offs[(size_t)k * NPIX + n];
    wtr[k] = wts[(size_t)k * NPIX + n];
  }

  uint_t pkw[36];
#pragma unroll
  for (int i = 0; i < 36; ++i) pkw[i] = 0u;

  f32x2a a0[9], b0[9], a1[9], b1[9];
  const size_t G0 = (size_t)9 * (part * 4 + wid);

#define SB __builtin_amdgcn_sched_barrier(0);
#define SLOAD(A_, B_, CL)                                                     \
  { const float* xc_ = xc0 + (CL) * HWSZ;                                     \
    _Pragma("unroll") for (int k = 0; k < 9; ++k) {                           \
      A_[k] = *(const f32x2a*)(xc_ + (ofr[k] & 0xffffu));                     \
      B_[k] = *(const f32x2a*)(xc_ + (ofr[k] >> 16)); } }
#define SCONS(A_, B_, CL)                                                     \
  { _Pragma("unroll") for (int k = 0; k < 9; ++k) {                           \
      float v_ = wtr[k].x * A_[k].x + wtr[k].y * A_[k].y +                    \
                 wtr[k].z * B_[k].x + wtr[k].w * B_[k].y;                     \
      const int q_ = 9 * (CL) + k;                                            \
      pkw[q_ >> 1] |= ((uint_t)f2bf(v_)) << ((q_ & 1) * 16); } }
#define SSTORE(G)                                                             \
  { uint4 st_ = make_uint4(pkw[4 * (G)], pkw[4 * (G) + 1],                    \
                           pkw[4 * (G) + 2], pkw[4 * (G) + 3]);               \
    *(uint4*)&S_g[((G0 + (G)) * NPIX + n) * 8] = st_; }

  SLOAD(a0, b0, 0)
  SLOAD(a1, b1, 1)
  SB
  SCONS(a0, b0, 0) SLOAD(a0, b0, 2) SSTORE(0) SB
  SCONS(a1, b1, 1) SLOAD(a1, b1, 3) SSTORE(1) SB
  SCONS(a0, b0, 2) SLOAD(a0, b0, 4) SSTORE(2) SB
  SCONS(a1, b1, 3) SLOAD(a1, b1, 5) SSTORE(3) SB
  SCONS(a0, b0, 4) SLOAD(a0, b0, 6) SSTORE(4) SB
  SCONS(a1, b1, 5) SLOAD(a1, b1, 7) SSTORE(5) SB
  SCONS(a0, b0, 6) SSTORE(6) SB
  SCONS(a1, b1, 7) SSTORE(7) SSTORE(8)
#undef SB
#undef SLOAD
#undef SCONS
#undef SSTORE
}

// ---------------- s_gemm: out = W9 * S + b_dcn ----------------
// BM=256, BN=64, BK=32, 72 chunks, grid 288, 512 thr / 8 waves, wave 64x32.
__global__ __launch_bounds__(512, 4) void s_gemm(
    const ushort_t* __restrict__ w9r, const ushort_t* __restrict__ S_g,
    const float* __restrict__ b_dcn, float* __restrict__ out) {
  __shared__ __align__(16) ushort_t A[2][8192];   // 32 KB
  __shared__ __align__(16) ushort_t S[2][2048];   // 8 KB

  const int tid = threadIdx.x;
  const int lane = tid & 63, wid = tid >> 6;
  const int p0 = blockIdx.x * 64;
  const int bimg = p0 / HWSZ;
  const int hw0 = p0 - bimg * HWSZ;
  const int lg = lane >> 4, lm = lane & 15;
  const int wr = wid >> 1, wc = wid & 1;

  f32x4 acc[4][2];
#pragma unroll
  for (int i = 0; i < 4; ++i)
#pragma unroll
    for (int j = 0; j < 2; ++j) acc[i][j] = (f32x4){0.f, 0.f, 0.f, 0.f};

#define SG_STAGE(CH, BUF)                                                     \
  {                                                                           \
    gload16(w9r + (size_t)(CH) * 8192 + tid * 8, &A[BUF][wid * 512]);         \
    gload16(w9r + (size_t)(CH) * 8192 + 4096 + tid * 8, &A[BUF][4096 + wid * 512]); \
    if (wid < 4)                                                              \
      gload16(S_g + ((size_t)((CH) * 4 + wid) * NPIX + p0 + lane) * 8,        \
              &S[BUF][wid * 512]);                                            \
  }
#define SG_MFMA(BUF)                                                          \
  {                                                                           \
    bf16x8 bfr0 = *(const bf16x8*)&S[BUF][(lg * 64 + wc * 32 + lm) * 8];      \
    bf16x8 bfr1 = *(const bf16x8*)&S[BUF][(lg * 64 + wc * 32 + 16 + lm) * 8]; \
    _Pragma("unroll") for (int mi = 0; mi < 4; ++mi) {                        \
      bf16x8 af = *(const bf16x8*)&A[BUF][(lg * 256 + wr * 64 + mi * 16 + lm) * 8]; \
      acc[mi][0] = __builtin_amdgcn_mfma_f32_16x16x32_bf16(af, bfr0, acc[mi][0], 0, 0, 0); \
      acc[mi][1] = __builtin_amdgcn_mfma_f32_16x16x32_bf16(af, bfr1, acc[mi][1], 0, 0, 0); \
    }                                                                         \
  }

  SG_STAGE(0, 0)
  for (int ko = 0; ko < 71; ++ko) {
    const int cur = ko & 1, nxt = cur ^ 1;
    SG_STAGE(ko + 1, nxt)
    if (wid < 4) { asm volatile("s_waitcnt vmcnt(3)" ::: "memory"); }
    else         { asm volatile("s_waitcnt vmcnt(2)" ::: "memory"); }
    __builtin_amdgcn_s_barrier();
    __builtin_amdgcn_sched_barrier(0);
    SG_MFMA(cur)
    asm volatile("s_waitcnt lgkmcnt(0)" ::: "memory");
    __builtin_amdgcn_s_barrier();
    __builtin_amdgcn_sched_barrier(0);
  }
  asm volatile("s_waitcnt vmcnt(0) lgkmcnt(0)" ::: "memory");
  __builtin_amdgcn_s_barrier();
  __builtin_amdgcn_sched_barrier(0);
  SG_MFMA(1)
#undef SG_STAGE
#undef SG_MFMA

  const int hwv0 = hw0 + wc * 32 + lm;
#pragma unroll
  for (int mi = 0; mi < 4; ++mi) {
    int obase = wr * 64 + mi * 16 + lg * 4;
#pragma unroll
    for (int ni = 0; ni < 2; ++ni)
#pragma unroll
      for (int r = 0; r < 4; ++r) {
        int o = obase + r;
        out[((size_t)(bimg * CO + o)) * HWSZ + hwv0 + ni * 16] = acc[mi][ni][r] + b_dcn[o];
      }
  }
}

// ---------------- BN stats, two-stage ----------------
__global__ __launch_bounds__(256) void bn_stats1(const float* __restrict__ out,
                                                 float2* __restrict__ part) {
  int o = blockIdx.x, s = blockIdx.y, tid = threadIdx.x;
  const float4* p = (const float4*)(out + ((size_t)((s >> 1) * CO + o)) * HWSZ + (s & 1) * 4608);
  float sum = 0.f, sq = 0.f;
#pragma unroll
  for (int j = tid; j < 1152; j += 256) {
    float4 v = p[j];
    sum += v.x + v.y + v.z + v.w;
    sq += v.x * v.x + v.y * v.y + v.z * v.z + v.w * v.w;
  }
#pragma unroll
  for (int off = 32; off > 0; off >>= 1) {
    sum += __shfl_xor(sum, off);
    sq += __shfl_xor(sq, off);
  }
  __shared__ float rs[4], rq[4];
  if ((tid & 63) == 0) { rs[tid >> 6] = sum; rq[tid >> 6] = sq; }
  __syncthreads();
  if (tid == 0)
    part[o * 4 + s] = make_float2(rs[0] + rs[1] + rs[2] + rs[3],
                                  rq[0] + rq[1] + rq[2] + rq[3]);
}

__global__ __launch_bounds__(256) void bn_finl(const float2* __restrict__ part,
                                               const float* __restrict__ gamma,
                                               const float* __restrict__ beta,
                                               float* __restrict__ ss) {
  int o = threadIdx.x;
  float s = 0.f, sq = 0.f;
#pragma unroll
  for (int i = 0; i < 4; ++i) {
    float2 p = part[o * 4 + i];
    s += p.x; sq += p.y;
  }
  float mean = s * (1.f / (float)NPIX);
  float var = sq * (1.f / (float)NPIX) - mean * mean;
  float rstd = rsqrtf(var + 1e-5f);
  float sc = rstd * gamma[o];
  ss[o] = sc;
  ss[CO + o] = beta[o] - mean * sc;
}

// ---------------- BN apply + ReLU ----------------
__global__ void bn_apply(float* __restrict__ out, const float* __restrict__ ss) {
  int i = blockIdx.x * 256 + threadIdx.x;
  float4 v = ((float4*)out)[i];
  int o = (i / (HWSZ / 4)) & 255;
  float sc = ss[o], sh = ss[CO + o];
  v.x = fmaxf(v.x * sc + sh, 0.f);
  v.y = fmaxf(v.y * sc + sh, 0.f);
  v.z = fmaxf(v.z * sc + sh, 0.f);
  v.w = fmaxf(v.w * sc + sh, 0.f);
  ((float4*)out)[i] = v;
}

extern "C" void kernel_launch(void* const* d_in, const int* in_sizes, int n_in,
                              void* d_out, int out_size, void* d_ws, size_t ws_size,
                              hipStream_t stream) {
  const float* x = (const float*)d_in[0];
  const float* w_off = (const float*)d_in[1];
  const float* b_off = (const float*)d_in[2];
  const float* w_dcn = (const float*)d_in[3];
  const float* b_dcn = (const float*)d_in[4];
  const float* gamma = (const float*)d_in[5];
  const float* beta = (const float*)d_in[6];
  float* out = (float*)d_out;

  char* ws = (char*)d_ws;

  size_t base = 84934656;                      // S_g occupies [0, base)
  ushort_t* S_g   = (ushort_t*)(ws);
  float*    om    = (float*)(ws + base);                    // 2*27*NPIX*4 = 3,981,312
  uint_t*   offs  = (uint_t*)(ws + base + 3981312);         //   663,552
  float4*   wts   = (float4*)(ws + base + 4644864);         // 2,654,208
  ushort_t* w9r   = (ushort_t*)(ws + base + 7299072);       // 1,179,648
  ushort_t* w27r  = (ushort_t*)(ws + base + 8478720);       //   147,456
  float*    ss    = (float*)(ws + base + 8626176);          //     2,048
  float2*   bnp   = (float2*)(ws + base + 8628224);         //     8,192

  cvt_w9<<<(CO * KTOT) / 256, 256, 0, stream>>>(w_dcn, w9r);
  cvt_woff9<<<(32 * KTOT) / 256, 256, 0, stream>>>(w_off, w27r);
  off_gemm<<<dim3(NPIX / 64, 2), 512, 0, stream>>>(x, w27r, om);
  prep_kernel<<<NPIX / 128, 128, 0, stream>>>(om, b_off, offs, wts);
  sample_s<<<dim3(NPIX / 64, 8), 256, 0, stream>>>(x, offs, wts, S_g);
  s_gemm<<<NPIX / 64, 512, 0, stream>>>(w9r, S_g, b_dcn, out);
  bn_stats1<<<dim3(CO, 4), 256, 0, stream>>>(out, bnp);
  bn_finl<<<1, 256, 0, stream>>>(bnp, gamma, beta, ss);
  bn_apply<<<(out_size / 4) / 256, 256, 0, stream>>>(out, ss);
}

// Round 14
// 213.720 us; speedup vs baseline: 1.3211x; 1.3211x over previous
//
#include <hip/hip_runtime.h>

// DeformConv fused pipeline, MI355X gfx950. Shapes: B=2, Ci=Co=256, H=W=96.
// R14 = R13 with the pkw packing bug fixed (pkw[4] clobber: q=9 OR'd at k=0,
// then q=8 assignment at k=8 overwrote it). pkw now zero-init + OR always.
//  - sample_s: thread = 2 channels -> ALL 36 gathers in ONE straight-line
//    region (MLP=36, no loop, no fences). Wave = 1 c-pair; grid 288x32.

typedef unsigned short ushort_t;
typedef unsigned int uint_t;
typedef __attribute__((ext_vector_type(8))) short bf16x8;
typedef __attribute__((ext_vector_type(4))) float f32x4;
typedef __attribute__((ext_vector_type(2), aligned(4))) float f32x2a;

#define HH 96
#define WW 96
#define HWSZ 9216
#define CI 256
#define CO 256
#define NB 2
#define NPIX 18432
#define KTOT 2304

__device__ __forceinline__ ushort_t f2bf(float f) {
  unsigned int u = __float_as_uint(f);
  u += 0x7fffu + ((u >> 16) & 1u);
  return (ushort_t)(u >> 16);
}
__device__ __forceinline__ float u2f(uint_t u) { return __uint_as_float(u); }

__device__ __forceinline__ void gload16(const void* g, void* l) {
  __builtin_amdgcn_global_load_lds(
      (const __attribute__((address_space(1))) unsigned int*)g,
      (__attribute__((address_space(3))) unsigned int*)l, 16, 0, 0);
}

// ---------------- cvt_w9: w_dcn -> bf16 [kk>>3][m][kk&7] ----------------
__global__ void cvt_w9(const float* __restrict__ w, ushort_t* __restrict__ o) {
  int i = blockIdx.x * 256 + threadIdx.x;      // grid exact CO*KTOT
  int oo = i / KTOT;
  int kk = i - oo * KTOT;
  o[(kk >> 3) * 2048 + oo * 8 + (kk & 7)] = f2bf(w[i]);
}

// ---------------- cvt_woff9: w_off -> bf16 [kk>>3][m32][kk&7], rows>=27 zero ----
__global__ void cvt_woff9(const float* __restrict__ w, ushort_t* __restrict__ o) {
  int i = blockIdx.x * 256 + threadIdx.x;      // grid exact 32*KTOT
  int m = i / KTOT;
  int kk = i - m * KTOT;
  float v = (m < 27) ? w[m * KTOT + kk] : 0.f;
  o[(kk >> 3) * 256 + m * 8 + (kk & 7)] = f2bf(v);
}

// ---------------- off_gemm: om_part[part][27][NPIX], K-split halves ----------------
__global__ __launch_bounds__(512, 2) void off_gemm(
    const float* __restrict__ x, const ushort_t* __restrict__ w27r,
    float* __restrict__ om_part) {
  __shared__ __align__(16) ushort_t A27[2][2048];
  __shared__ __align__(16) ushort_t B64[4096];
  __shared__ uint2 tbl[9][64];                 // {abs idx (0 if invalid), mask}

  const int tid = threadIdx.x;
  const int lane = tid & 63, wid = tid >> 6;
  const int p0 = blockIdx.x * 64;
  const int part = blockIdx.y;                 // K half
  const int bimg = p0 / HWSZ;
  const int hw0 = p0 - bimg * HWSZ;
  const float* xb = x + (size_t)bimg * CI * HWSZ;

  for (int e = tid; e < 576; e += 512) {
    int k = e >> 6, px = e & 63;
    int hw = hw0 + px, h = hw / WW, w_ = hw - h * WW;
    int dy = k / 3 - 1, dx = k % 3 - 1;
    bool ok = (h + dy >= 0) && (h + dy < HH) && (w_ + dx >= 0) && (w_ + dx < WW);
    tbl[k][px] = make_uint2(ok ? (uint_t)(hw + dy * WW + dx) : 0u,
                            ok ? 0x3f800000u : 0u);
  }

  const int lg = lane >> 4, lm = lane & 15;
  const int wr = wid >> 2, wc = wid & 3;
  f32x4 acc = (f32x4){0.f, 0.f, 0.f, 0.f};

  int cj[8], kj[8];
#pragma unroll
  for (int j = 0; j < 8; ++j) {
    int kk = part * 1152 + wid * 8 + j;
    cj[j] = kk / 9;
    kj[j] = kk - 9 * cj[j];
  }
  __syncthreads();

  float rv0[8], rm0[8], rv1[8], rm1[8];
  const int k0 = part * 18;

#define OG_RAW(RV, RM)                                                        \
  { _Pragma("unroll") for (int j = 0; j < 8; ++j) {                           \
      uint2 e_ = tbl[kj[j]][lane];                                            \
      RV[j] = xb[cj[j] * HWSZ + (int)e_.x];                                   \
      RM[j] = u2f(e_.y);                                                      \
      kj[j] += 1; cj[j] += 7;                                                 \
      if (kj[j] == 9) { kj[j] = 0; cj[j] += 1; } } }
#define OG_GA(CH, BUF)                                                        \
  gload16(w27r + (size_t)(CH) * 2048 + (tid & 255) * 8, &A27[BUF][(wid & 3) * 512]);
#define OG_STEP(CUR, RVC, RMC, RVN, RMN, KO)                                  \
  {                                                                           \
    if ((KO) < 17) {                                                          \
      OG_RAW(RVN, RMN)                                                        \
      OG_GA(k0 + (KO) + 1, (CUR) ^ 1)                                         \
      asm volatile("s_waitcnt vmcnt(10)" ::: "memory");                       \
    } else {                                                                  \
      asm volatile("s_waitcnt vmcnt(1)" ::: "memory");                        \
    }                                                                         \
    __builtin_amdgcn_sched_barrier(0);                                        \
    {                                                                         \
      ushort_t sv_[8] __attribute__((aligned(16)));                           \
      _Pragma("unroll") for (int j = 0; j < 8; ++j)                           \
        sv_[j] = f2bf(RVC[j] * RMC[j]);                                       \
      *(uint4*)&B64[tid * 8] = *(const uint4*)sv_;                            \
    }                                                                         \
    if ((KO) < 17) asm volatile("s_waitcnt vmcnt(9) lgkmcnt(0)" ::: "memory"); \
    else           asm volatile("s_waitcnt vmcnt(0) lgkmcnt(0)" ::: "memory"); \
    __builtin_amdgcn_s_barrier();                                             \
    __builtin_amdgcn_sched_barrier(0);                                        \
    _Pragma("unroll") for (int s = 0; s < 2; ++s) {                           \
      bf16x8 af = *(const bf16x8*)&A27[CUR][((s * 4 + lg) * 32 + wr * 16 + lm) * 8]; \
      bf16x8 bfv = *(const bf16x8*)&B64[((s * 4 + lg) * 64 + wc * 16 + lm) * 8];     \
      acc = __builtin_amdgcn_mfma_f32_16x16x32_bf16(af, bfv, acc, 0, 0, 0);   \
    }                                                                         \
    asm volatile("s_waitcnt lgkmcnt(0)" ::: "memory");                        \
    __builtin_amdgcn_s_barrier();                                             \
    __builtin_amdgcn_sched_barrier(0);                                        \
  }

  OG_RAW(rv0, rm0)
  OG_GA(k0, 0)
  for (int ko2 = 0; ko2 < 9; ++ko2) {
    const int ko = ko2 * 2;
    OG_STEP(0, rv0, rm0, rv1, rm1, ko)
    OG_STEP(1, rv1, rm1, rv0, rm0, ko + 1)
  }
#undef OG_RAW
#undef OG_GA
#undef OG_STEP

  int row = wr * 16 + lg * 4;
  int col = p0 + wc * 16 + lm;
#pragma unroll
  for (int r = 0; r < 4; ++r)
    if (row + r < 27)
      om_part[((size_t)(part * 27 + row + r)) * NPIX + col] = acc[r];
}

// ---------------- prep: sum om halves -> row-pair offsets + folded weights ----------------
__global__ void prep_kernel(const float* __restrict__ om_part, const float* __restrict__ b_off,
                            uint_t* __restrict__ offs, float4* __restrict__ wts) {
  int n = blockIdx.x * 128 + threadIdx.x;      // grid 144 x 128
  float omv[27];
#pragma unroll
  for (int ch = 0; ch < 27; ++ch)
    omv[ch] = b_off[ch] + om_part[(size_t)ch * NPIX + n] +
              om_part[((size_t)(27 + ch)) * NPIX + n];
  int hw = n % HWSZ;
  int h = hw / WW, w = hw - h * WW;
#pragma unroll
  for (int k = 0; k < 9; ++k) {
    float dy = omv[2 * k], dx = omv[2 * k + 1];
    float mk = 1.f / (1.f + __expf(-omv[18 + k]));
    float py = dy + (float)(h - 1 + k / 3);
    float px = dx + (float)(w - 1 + k % 3);
    float y0f = floorf(py), x0f = floorf(px);
    int y0 = (int)y0f, x0 = (int)x0f;
    float wy1 = py - y0f, wx1 = px - x0f;
    float wy0 = 1.f - wy1, wx0 = 1.f - wx1;
    float vy0 = (y0 >= 0 && y0 <= HH - 1) ? 1.f : 0.f;
    float vy1 = (y0 + 1 >= 0 && y0 + 1 <= HH - 1) ? 1.f : 0.f;
    int yc0 = min(max(y0, 0), HH - 1), yc1 = min(max(y0 + 1, 0), HH - 1);
    int xa = min(max(x0, 0), WW - 2);
    float a_, b_;
    if (x0 >= 0 && x0 <= WW - 2)      { a_ = wx0; b_ = wx1; }
    else if (x0 == -1)                { a_ = wx1; b_ = 0.f; }
    else if (x0 == WW - 1)            { a_ = 0.f; b_ = wx0; }
    else                              { a_ = 0.f; b_ = 0.f; }
    float s0 = mk * vy0 * wy0, s1 = mk * vy1 * wy1;
    offs[(size_t)k * NPIX + n] = (uint_t)(yc0 * WW + xa) | ((uint_t)(yc1 * WW + xa) << 16);
    wts[(size_t)k * NPIX + n] = make_float4(a_ * s0, b_ * s0, a_ * s1, b_ * s1);
  }
}

// ---------------- sample_s: S_g[kk>>3][n][kk&7] bf16 ----------------
// Grid 288 x 32; 256 thr = 4 waves; wave = ONE channel-pair (cp = part*4+wid).
// ALL 36 gathers issued in one straight-line region (MLP=36). 18 kk -> 9
// aligned uint stores. pkw zero-init + OR (R13 clobber bug fixed).
__global__ __launch_bounds__(256, 3) void sample_s(
    const float* __restrict__ x, const uint_t* __restrict__ offs,
    const float4* __restrict__ wts, ushort_t* __restrict__ S_g) {
  const int tid = threadIdx.x;
  const int lane = tid & 63, wid = tid >> 6;   // 4 waves
  const int p0 = blockIdx.x * 64;
  const int cp = blockIdx.y * 4 + wid;         // c-pair 0..127
  const int n = p0 + lane;
  const int bimg = p0 / HWSZ;
  const float* xc0 = x + ((size_t)bimg * CI + cp * 2) * HWSZ;
  const float* xc1 = xc0 + HWSZ;

  uint_t ofr[9]; float4 wtr[9];
#pragma unroll
  for (int k = 0; k < 9; ++k) {
    ofr[k] = offs[(size_t)k * NPIX + n];
    wtr[k] = wts[(size_t)k * NPIX + n];
  }

  // ---- 36 independent gathers, one region ----
  f32x2a a0[9], b0[9], a1[9], b1[9];
#pragma unroll
  for (int k = 0; k < 9; ++k) {
    const int o0 = (int)(ofr[k] & 0xffffu);
    const int o1 = (int)(ofr[k] >> 16);
    a0[k] = *(const f32x2a*)(xc0 + o0);
    b0[k] = *(const f32x2a*)(xc0 + o1);
    a1[k] = *(const f32x2a*)(xc1 + o0);
    b1[k] = *(const f32x2a*)(xc1 + o1);
  }

  // ---- consume -> 18 bf16 -> 9 uints (zero-init + OR, no clobber) ----
  uint_t pkw[9];
#pragma unroll
  for (int i = 0; i < 9; ++i) pkw[i] = 0u;
#pragma unroll
  for (int k = 0; k < 9; ++k) {
    float v0 = wtr[k].x * a0[k].x + wtr[k].y * a0[k].y +
               wtr[k].z * b0[k].x + wtr[k].w * b0[k].y;
    float v1 = wtr[k].x * a1[k].x + wtr[k].y * a1[k].y +
               wtr[k].z * b1[k].x + wtr[k].w * b1[k].y;
    const int q0 = k, q1 = 9 + k;
    pkw[q0 >> 1] |= ((uint_t)f2bf(v0)) << ((q0 & 1) * 16);
    pkw[q1 >> 1] |= ((uint_t)f2bf(v1)) << ((q1 & 1) * 16);
  }

  // ---- 9 aligned uint stores: kk = cp*18 + 2j ----
#pragma unroll
  for (int j = 0; j < 9; ++j) {
    const int kk = cp * 18 + 2 * j;
    *(uint_t*)&S_g[((size_t)(kk >> 3) * NPIX + n) * 8 + (kk & 7)] = pkw[j];
  }
}

// ---------------- s_gemm: out = W9 * S + b_dcn ----------------
// BM=256, BN=64, BK=32, 72 chunks, grid 288, 512 thr / 8 waves, wave 64x32.
__global__ __launch_bounds__(512, 4) void s_gemm(
    const ushort_t* __restrict__ w9r, const ushort_t* __restrict__ S_g,
    const float* __restrict__ b_dcn, float* __restrict__ out) {
  __shared__ __align__(16) ushort_t A[2][8192];   // 32 KB
  __shared__ __align__(16) ushort_t S[2][2048];   // 8 KB

  const int tid = threadIdx.x;
  const int lane = tid & 63, wid = tid >> 6;
  const int p0 = blockIdx.x * 64;
  const int bimg = p0 / HWSZ;
  const int hw0 = p0 - bimg * HWSZ;
  const int lg = lane >> 4, lm = lane & 15;
  const int wr = wid >> 1, wc = wid & 1;

  f32x4 acc[4][2];
#pragma unroll
  for (int i = 0; i < 4; ++i)
#pragma unroll
    for (int j = 0; j < 2; ++j) acc[i][j] = (f32x4){0.f, 0.f, 0.f, 0.f};

#define SG_STAGE(CH, BUF)                                                     \
  {                                                                           \
    gload16(w9r + (size_t)(CH) * 8192 + tid * 8, &A[BUF][wid * 512]);         \
    gload16(w9r + (size_t)(CH) * 8192 + 4096 + tid * 8, &A[BUF][4096 + wid * 512]); \
    if (wid < 4)                                                              \
      gload16(S_g + ((size_t)((CH) * 4 + wid) * NPIX + p0 + lane) * 8,        \
              &S[BUF][wid * 512]);                                            \
  }
#define SG_MFMA(BUF)                                                          \
  {                                                                           \
    bf16x8 bfr0 = *(const bf16x8*)&S[BUF][(lg * 64 + wc * 32 + lm) * 8];      \
    bf16x8 bfr1 = *(const bf16x8*)&S[BUF][(lg * 64 + wc * 32 + 16 + lm) * 8]; \
    _Pragma("unroll") for (int mi = 0; mi < 4; ++mi) {                        \
      bf16x8 af = *(const bf16x8*)&A[BUF][(lg * 256 + wr * 64 + mi * 16 + lm) * 8]; \
      acc[mi][0] = __builtin_amdgcn_mfma_f32_16x16x32_bf16(af, bfr0, acc[mi][0], 0, 0, 0); \
      acc[mi][1] = __builtin_amdgcn_mfma_f32_16x16x32_bf16(af, bfr1, acc[mi][1], 0, 0, 0); \
    }                                                                         \
  }

  SG_STAGE(0, 0)
  for (int ko = 0; ko < 71; ++ko) {
    const int cur = ko & 1, nxt = cur ^ 1;
    SG_STAGE(ko + 1, nxt)
    if (wid < 4) { asm volatile("s_waitcnt vmcnt(3)" ::: "memory"); }
    else         { asm volatile("s_waitcnt vmcnt(2)" ::: "memory"); }
    __builtin_amdgcn_s_barrier();
    __builtin_amdgcn_sched_barrier(0);
    SG_MFMA(cur)
    asm volatile("s_waitcnt lgkmcnt(0)" ::: "memory");
    __builtin_amdgcn_s_barrier();
    __builtin_amdgcn_sched_barrier(0);
  }
  asm volatile("s_waitcnt vmcnt(0) lgkmcnt(0)" ::: "memory");
  __builtin_amdgcn_s_barrier();
  __builtin_amdgcn_sched_barrier(0);
  SG_MFMA(1)
#undef SG_STAGE
#undef SG_MFMA

  const int hwv0 = hw0 + wc * 32 + lm;
#pragma unroll
  for (int mi = 0; mi < 4; ++mi) {
    int obase = wr * 64 + mi * 16 + lg * 4;
#pragma unroll
    for (int ni = 0; ni < 2; ++ni)
#pragma unroll
      for (int r = 0; r < 4; ++r) {
        int o = obase + r;
        out[((size_t)(bimg * CO + o)) * HWSZ + hwv0 + ni * 16] = acc[mi][ni][r] + b_dcn[o];
      }
  }
}

// ---------------- BN stats, two-stage ----------------
__global__ __launch_bounds__(256) void bn_stats1(const float* __restrict__ out,
                                                 float2* __restrict__ part) {
  int o = blockIdx.x, s = blockIdx.y, tid = threadIdx.x;
  const float4* p = (const float4*)(out + ((size_t)((s >> 1) * CO + o)) * HWSZ + (s & 1) * 4608);
  float sum = 0.f, sq = 0.f;
#pragma unroll
  for (int j = tid; j < 1152; j += 256) {
    float4 v = p[j];
    sum += v.x + v.y + v.z + v.w;
    sq += v.x * v.x + v.y * v.y + v.z * v.z + v.w * v.w;
  }
#pragma unroll
  for (int off = 32; off > 0; off >>= 1) {
    sum += __shfl_xor(sum, off);
    sq += __shfl_xor(sq, off);
  }
  __shared__ float rs[4], rq[4];
  if ((tid & 63) == 0) { rs[tid >> 6] = sum; rq[tid >> 6] = sq; }
  __syncthreads();
  if (tid == 0)
    part[o * 4 + s] = make_float2(rs[0] + rs[1] + rs[2] + rs[3],
                                  rq[0] + rq[1] + rq[2] + rq[3]);
}

__global__ __launch_bounds__(256) void bn_finl(const float2* __restrict__ part,
                                               const float* __restrict__ gamma,
                                               const float* __restrict__ beta,
                                               float* __restrict__ ss) {
  int o = threadIdx.x;
  float s = 0.f, sq = 0.f;
#pragma unroll
  for (int i = 0; i < 4; ++i) {
    float2 p = part[o * 4 + i];
    s += p.x; sq += p.y;
  }
  float mean = s * (1.f / (float)NPIX);
  float var = sq * (1.f / (float)NPIX) - mean * mean;
  float rstd = rsqrtf(var + 1e-5f);
  float sc = rstd * gamma[o];
  ss[o] = sc;
  ss[CO + o] = beta[o] - mean * sc;
}

// ---------------- BN apply + ReLU ----------------
__global__ void bn_apply(float* __restrict__ out, const float* __restrict__ ss) {
  int i = blockIdx.x * 256 + threadIdx.x;
  float4 v = ((float4*)out)[i];
  int o = (i / (HWSZ / 4)) & 255;
  float sc = ss[o], sh = ss[CO + o];
  v.x = fmaxf(v.x * sc + sh, 0.f);
  v.y = fmaxf(v.y * sc + sh, 0.f);
  v.z = fmaxf(v.z * sc + sh, 0.f);
  v.w = fmaxf(v.w * sc + sh, 0.f);
  ((float4*)out)[i] = v;
}

extern "C" void kernel_launch(void* const* d_in, const int* in_sizes, int n_in,
                              void* d_out, int out_size, void* d_ws, size_t ws_size,
                              hipStream_t stream) {
  const float* x = (const float*)d_in[0];
  const float* w_off = (const float*)d_in[1];
  const float* b_off = (const float*)d_in[2];
  const float* w_dcn = (const float*)d_in[3];
  const float* b_dcn = (const float*)d_in[4];
  const float* gamma = (const float*)d_in[5];
  const float* beta = (const float*)d_in[6];
  float* out = (float*)d_out;

  char* ws = (char*)d_ws;

  size_t base = 84934656;                      // S_g occupies [0, base)
  ushort_t* S_g   = (ushort_t*)(ws);
  float*    om    = (float*)(ws + base);                    // 2*27*NPIX*4 = 3,981,312
  uint_t*   offs  = (uint_t*)(ws + base + 3981312);         //   663,552
  float4*   wts   = (float4*)(ws + base + 4644864);         // 2,654,208
  ushort_t* w9r   = (ushort_t*)(ws + base + 7299072);       // 1,179,648
  ushort_t* w27r  = (ushort_t*)(ws + base + 8478720);       //   147,456
  float*    ss    = (float*)(ws + base + 8626176);          //     2,048
  float2*   bnp   = (float2*)(ws + base + 8628224);         //     8,192

  cvt_w9<<<(CO * KTOT) / 256, 256, 0, stream>>>(w_dcn, w9r);
  cvt_woff9<<<(32 * KTOT) / 256, 256, 0, stream>>>(w_off, w27r);
  off_gemm<<<dim3(NPIX / 64, 2), 512, 0, stream>>>(x, w27r, om);
  prep_kernel<<<NPIX / 128, 128, 0, stream>>>(om, b_off, offs, wts);
  sample_s<<<dim3(NPIX / 64, 32), 256, 0, stream>>>(x, offs, wts, S_g);
  s_gemm<<<NPIX / 64, 512, 0, stream>>>(w9r, S_g, b_dcn, out);
  bn_stats1<<<dim3(CO, 4), 256, 0, stream>>>(out, bnp);
  bn_finl<<<1, 256, 0, stream>>>(bnp, gamma, beta, ss);
  bn_apply<<<(out_size / 4) / 256, 256, 0, stream>>>(out, ss);
}

// Round 15
// 159.465 us; speedup vs baseline: 1.7706x; 1.3402x over previous
//
#include <hip/hip_runtime.h>

// DeformConv fused pipeline, MI355X gfx950. Shapes: B=2, Ci=Co=256, H=W=96.
// R15 changes vs R14 (sample_s ~100us across 3 schedules with optimal traffic
// -> L1 vector-gather path is the bottleneck, not scheduling):
//  - sample_lds: stage the 2-channel x slice (72 KB) into LDS once, gather
//    via ds_read2_b32 instead of 36 global gathers. Grid (4,128) = 512 blocks
//    = exactly 2/CU (144 KB LDS). Tables stream coalesced from L2.
//  - everything else identical to R14 (passing, 213us).

typedef unsigned short ushort_t;
typedef unsigned int uint_t;
typedef __attribute__((ext_vector_type(8))) short bf16x8;
typedef __attribute__((ext_vector_type(4))) float f32x4;
typedef __attribute__((ext_vector_type(2), aligned(4))) float f32x2a;

#define HH 96
#define WW 96
#define HWSZ 9216
#define CI 256
#define CO 256
#define NB 2
#define NPIX 18432
#define KTOT 2304

__device__ __forceinline__ ushort_t f2bf(float f) {
  unsigned int u = __float_as_uint(f);
  u += 0x7fffu + ((u >> 16) & 1u);
  return (ushort_t)(u >> 16);
}
__device__ __forceinline__ float u2f(uint_t u) { return __uint_as_float(u); }

__device__ __forceinline__ void gload16(const void* g, void* l) {
  __builtin_amdgcn_global_load_lds(
      (const __attribute__((address_space(1))) unsigned int*)g,
      (__attribute__((address_space(3))) unsigned int*)l, 16, 0, 0);
}

// ---------------- cvt_w9: w_dcn -> bf16 [kk>>3][m][kk&7] ----------------
__global__ void cvt_w9(const float* __restrict__ w, ushort_t* __restrict__ o) {
  int i = blockIdx.x * 256 + threadIdx.x;      // grid exact CO*KTOT
  int oo = i / KTOT;
  int kk = i - oo * KTOT;
  o[(kk >> 3) * 2048 + oo * 8 + (kk & 7)] = f2bf(w[i]);
}

// ---------------- cvt_woff9: w_off -> bf16 [kk>>3][m32][kk&7], rows>=27 zero ----
__global__ void cvt_woff9(const float* __restrict__ w, ushort_t* __restrict__ o) {
  int i = blockIdx.x * 256 + threadIdx.x;      // grid exact 32*KTOT
  int m = i / KTOT;
  int kk = i - m * KTOT;
  float v = (m < 27) ? w[m * KTOT + kk] : 0.f;
  o[(kk >> 3) * 256 + m * 8 + (kk & 7)] = f2bf(v);
}

// ---------------- off_gemm: om_part[part][27][NPIX], K-split halves ----------------
__global__ __launch_bounds__(512, 2) void off_gemm(
    const float* __restrict__ x, const ushort_t* __restrict__ w27r,
    float* __restrict__ om_part) {
  __shared__ __align__(16) ushort_t A27[2][2048];
  __shared__ __align__(16) ushort_t B64[4096];
  __shared__ uint2 tbl[9][64];                 // {abs idx (0 if invalid), mask}

  const int tid = threadIdx.x;
  const int lane = tid & 63, wid = tid >> 6;
  const int p0 = blockIdx.x * 64;
  const int part = blockIdx.y;                 // K half
  const int bimg = p0 / HWSZ;
  const int hw0 = p0 - bimg * HWSZ;
  const float* xb = x + (size_t)bimg * CI * HWSZ;

  for (int e = tid; e < 576; e += 512) {
    int k = e >> 6, px = e & 63;
    int hw = hw0 + px, h = hw / WW, w_ = hw - h * WW;
    int dy = k / 3 - 1, dx = k % 3 - 1;
    bool ok = (h + dy >= 0) && (h + dy < HH) && (w_ + dx >= 0) && (w_ + dx < WW);
    tbl[k][px] = make_uint2(ok ? (uint_t)(hw + dy * WW + dx) : 0u,
                            ok ? 0x3f800000u : 0u);
  }

  const int lg = lane >> 4, lm = lane & 15;
  const int wr = wid >> 2, wc = wid & 3;
  f32x4 acc = (f32x4){0.f, 0.f, 0.f, 0.f};

  int cj[8], kj[8];
#pragma unroll
  for (int j = 0; j < 8; ++j) {
    int kk = part * 1152 + wid * 8 + j;
    cj[j] = kk / 9;
    kj[j] = kk - 9 * cj[j];
  }
  __syncthreads();

  float rv0[8], rm0[8], rv1[8], rm1[8];
  const int k0 = part * 18;

#define OG_RAW(RV, RM)                                                        \
  { _Pragma("unroll") for (int j = 0; j < 8; ++j) {                           \
      uint2 e_ = tbl[kj[j]][lane];                                            \
      RV[j] = xb[cj[j] * HWSZ + (int)e_.x];                                   \
      RM[j] = u2f(e_.y);                                                      \
      kj[j] += 1; cj[j] += 7;                                                 \
      if (kj[j] == 9) { kj[j] = 0; cj[j] += 1; } } }
#define OG_GA(CH, BUF)                                                        \
  gload16(w27r + (size_t)(CH) * 2048 + (tid & 255) * 8, &A27[BUF][(wid & 3) * 512]);
#define OG_STEP(CUR, RVC, RMC, RVN, RMN, KO)                                  \
  {                                                                           \
    if ((KO) < 17) {                                                          \
      OG_RAW(RVN, RMN)                                                        \
      OG_GA(k0 + (KO) + 1, (CUR) ^ 1)                                         \
      asm volatile("s_waitcnt vmcnt(10)" ::: "memory");                       \
    } else {                                                                  \
      asm volatile("s_waitcnt vmcnt(1)" ::: "memory");                        \
    }                                                                         \
    __builtin_amdgcn_sched_barrier(0);                                        \
    {                                                                         \
      ushort_t sv_[8] __attribute__((aligned(16)));                           \
      _Pragma("unroll") for (int j = 0; j < 8; ++j)                           \
        sv_[j] = f2bf(RVC[j] * RMC[j]);                                       \
      *(uint4*)&B64[tid * 8] = *(const uint4*)sv_;                            \
    }                                                                         \
    if ((KO) < 17) asm volatile("s_waitcnt vmcnt(9) lgkmcnt(0)" ::: "memory"); \
    else           asm volatile("s_waitcnt vmcnt(0) lgkmcnt(0)" ::: "memory"); \
    __builtin_amdgcn_s_barrier();                                             \
    __builtin_amdgcn_sched_barrier(0);                                        \
    _Pragma("unroll") for (int s = 0; s < 2; ++s) {                           \
      bf16x8 af = *(const bf16x8*)&A27[CUR][((s * 4 + lg) * 32 + wr * 16 + lm) * 8]; \
      bf16x8 bfv = *(const bf16x8*)&B64[((s * 4 + lg) * 64 + wc * 16 + lm) * 8];     \
      acc = __builtin_amdgcn_mfma_f32_16x16x32_bf16(af, bfv, acc, 0, 0, 0);   \
    }                                                                         \
    asm volatile("s_waitcnt lgkmcnt(0)" ::: "memory");                        \
    __builtin_amdgcn_s_barrier();                                             \
    __builtin_amdgcn_sched_barrier(0);                                        \
  }

  OG_RAW(rv0, rm0)
  OG_GA(k0, 0)
  for (int ko2 = 0; ko2 < 9; ++ko2) {
    const int ko = ko2 * 2;
    OG_STEP(0, rv0, rm0, rv1, rm1, ko)
    OG_STEP(1, rv1, rm1, rv0, rm0, ko + 1)
  }
#undef OG_RAW
#undef OG_GA
#undef OG_STEP

  int row = wr * 16 + lg * 4;
  int col = p0 + wc * 16 + lm;
#pragma unroll
  for (int r = 0; r < 4; ++r)
    if (row + r < 27)
      om_part[((size_t)(part * 27 + row + r)) * NPIX + col] = acc[r];
}

// ---------------- prep: sum om halves -> row-pair offsets + folded weights ----------------
__global__ void prep_kernel(const float* __restrict__ om_part, const float* __restrict__ b_off,
                            uint_t* __restrict__ offs, float4* __restrict__ wts) {
  int n = blockIdx.x * 128 + threadIdx.x;      // grid 144 x 128
  float omv[27];
#pragma unroll
  for (int ch = 0; ch < 27; ++ch)
    omv[ch] = b_off[ch] + om_part[(size_t)ch * NPIX + n] +
              om_part[((size_t)(27 + ch)) * NPIX + n];
  int hw = n % HWSZ;
  int h = hw / WW, w = hw - h * WW;
#pragma unroll
  for (int k = 0; k < 9; ++k) {
    float dy = omv[2 * k], dx = omv[2 * k + 1];
    float mk = 1.f / (1.f + __expf(-omv[18 + k]));
    float py = dy + (float)(h - 1 + k / 3);
    float px = dx + (float)(w - 1 + k % 3);
    float y0f = floorf(py), x0f = floorf(px);
    int y0 = (int)y0f, x0 = (int)x0f;
    float wy1 = py - y0f, wx1 = px - x0f;
    float wy0 = 1.f - wy1, wx0 = 1.f - wx1;
    float vy0 = (y0 >= 0 && y0 <= HH - 1) ? 1.f : 0.f;
    float vy1 = (y0 + 1 >= 0 && y0 + 1 <= HH - 1) ? 1.f : 0.f;
    int yc0 = min(max(y0, 0), HH - 1), yc1 = min(max(y0 + 1, 0), HH - 1);
    int xa = min(max(x0, 0), WW - 2);
    float a_, b_;
    if (x0 >= 0 && x0 <= WW - 2)      { a_ = wx0; b_ = wx1; }
    else if (x0 == -1)                { a_ = wx1; b_ = 0.f; }
    else if (x0 == WW - 1)            { a_ = 0.f; b_ = wx0; }
    else                              { a_ = 0.f; b_ = 0.f; }
    float s0 = mk * vy0 * wy0, s1 = mk * vy1 * wy1;
    offs[(size_t)k * NPIX + n] = (uint_t)(yc0 * WW + xa) | ((uint_t)(yc1 * WW + xa) << 16);
    wts[(size_t)k * NPIX + n] = make_float4(a_ * s0, b_ * s0, a_ * s1, b_ * s1);
  }
}

// ---------------- sample_lds: S_g[kk>>3][n][kk&7] bf16 ----------------
// Grid (4, 128): blockIdx.x = img*2+half, blockIdx.y = c-pair. Block stages
// both channel images (72 KB LDS), gathers via ds_read2_b32, 9 px/thread.
__global__ __launch_bounds__(512, 2) void sample_lds(
    const float* __restrict__ x, const uint_t* __restrict__ offs,
    const float4* __restrict__ wts, ushort_t* __restrict__ S_g) {
  __shared__ float xl[2][HWSZ];                // 73,728 B
  const int tid = threadIdx.x;
  const int wid = tid >> 6;
  const int img = blockIdx.x >> 1;
  const int half = blockIdx.x & 1;
  const int cp = blockIdx.y;                   // 0..127
  const int n0 = img * HWSZ + half * 4608;

  // ---- stage 2 channel images: 18432 floats = 9 passes x 512 thr x 16B ----
  {
    const float* src = x + ((size_t)(img * CI + 2 * cp)) * HWSZ;
    float* dst = &xl[0][0];
#pragma unroll
    for (int i = 0; i < 9; ++i)
      gload16(src + i * 2048 + tid * 4, dst + i * 2048 + wid * 256);
  }
  __syncthreads();

  // ---- 9 pixels per thread ----
  for (int j = 0; j < 9; ++j) {
    const int n = n0 + tid + j * 512;
    uint_t ofr[9]; float4 wtr[9];
#pragma unroll
    for (int k = 0; k < 9; ++k) {
      ofr[k] = offs[(size_t)k * NPIX + n];
      wtr[k] = wts[(size_t)k * NPIX + n];
    }
    uint_t pkw[9];
#pragma unroll
    for (int i = 0; i < 9; ++i) pkw[i] = 0u;
#pragma unroll
    for (int k = 0; k < 9; ++k) {
      const int o0 = (int)(ofr[k] & 0xffffu);
      const int o1 = (int)(ofr[k] >> 16);
      float a0x = xl[0][o0], a0y = xl[0][o0 + 1];
      float b0x = xl[0][o1], b0y = xl[0][o1 + 1];
      float a1x = xl[1][o0], a1y = xl[1][o0 + 1];
      float b1x = xl[1][o1], b1y = xl[1][o1 + 1];
      float v0 = wtr[k].x * a0x + wtr[k].y * a0y + wtr[k].z * b0x + wtr[k].w * b0y;
      float v1 = wtr[k].x * a1x + wtr[k].y * a1y + wtr[k].z * b1x + wtr[k].w * b1y;
      const int q0 = k, q1 = 9 + k;
      pkw[q0 >> 1] |= ((uint_t)f2bf(v0)) << ((q0 & 1) * 16);
      pkw[q1 >> 1] |= ((uint_t)f2bf(v1)) << ((q1 & 1) * 16);
    }
#pragma unroll
    for (int jj = 0; jj < 9; ++jj) {
      const int kk = cp * 18 + 2 * jj;
      *(uint_t*)&S_g[((size_t)(kk >> 3) * NPIX + n) * 8 + (kk & 7)] = pkw[jj];
    }
  }
}

// ---------------- s_gemm: out = W9 * S + b_dcn ----------------
// BM=256, BN=64, BK=32, 72 chunks, grid 288, 512 thr / 8 waves, wave 64x32.
__global__ __launch_bounds__(512, 4) void s_gemm(
    const ushort_t* __restrict__ w9r, const ushort_t* __restrict__ S_g,
    const float* __restrict__ b_dcn, float* __restrict__ out) {
  __shared__ __align__(16) ushort_t A[2][8192];   // 32 KB
  __shared__ __align__(16) ushort_t S[2][2048];   // 8 KB

  const int tid = threadIdx.x;
  const int lane = tid & 63, wid = tid >> 6;
  const int p0 = blockIdx.x * 64;
  const int bimg = p0 / HWSZ;
  const int hw0 = p0 - bimg * HWSZ;
  const int lg = lane >> 4, lm = lane & 15;
  const int wr = wid >> 1, wc = wid & 1;

  f32x4 acc[4][2];
#pragma unroll
  for (int i = 0; i < 4; ++i)
#pragma unroll
    for (int j = 0; j < 2; ++j) acc[i][j] = (f32x4){0.f, 0.f, 0.f, 0.f};

#define SG_STAGE(CH, BUF)                                                     \
  {                                                                           \
    gload16(w9r + (size_t)(CH) * 8192 + tid * 8, &A[BUF][wid * 512]);         \
    gload16(w9r + (size_t)(CH) * 8192 + 4096 + tid * 8, &A[BUF][4096 + wid * 512]); \
    if (wid < 4)                                                              \
      gload16(S_g + ((size_t)((CH) * 4 + wid) * NPIX + p0 + lane) * 8,        \
              &S[BUF][wid * 512]);                                            \
  }
#define SG_MFMA(BUF)                                                          \
  {                                                                           \
    bf16x8 bfr0 = *(const bf16x8*)&S[BUF][(lg * 64 + wc * 32 + lm) * 8];      \
    bf16x8 bfr1 = *(const bf16x8*)&S[BUF][(lg * 64 + wc * 32 + 16 + lm) * 8]; \
    _Pragma("unroll") for (int mi = 0; mi < 4; ++mi) {                        \
      bf16x8 af = *(const bf16x8*)&A[BUF][(lg * 256 + wr * 64 + mi * 16 + lm) * 8]; \
      acc[mi][0] = __builtin_amdgcn_mfma_f32_16x16x32_bf16(af, bfr0, acc[mi][0], 0, 0, 0); \
      acc[mi][1] = __builtin_amdgcn_mfma_f32_16x16x32_bf16(af, bfr1, acc[mi][1], 0, 0, 0); \
    }                                                                         \
  }

  SG_STAGE(0, 0)
  for (int ko = 0; ko < 71; ++ko) {
    const int cur = ko & 1, nxt = cur ^ 1;
    SG_STAGE(ko + 1, nxt)
    if (wid < 4) { asm volatile("s_waitcnt vmcnt(3)" ::: "memory"); }
    else         { asm volatile("s_waitcnt vmcnt(2)" ::: "memory"); }
    __builtin_amdgcn_s_barrier();
    __builtin_amdgcn_sched_barrier(0);
    SG_MFMA(cur)
    asm volatile("s_waitcnt lgkmcnt(0)" ::: "memory");
    __builtin_amdgcn_s_barrier();
    __builtin_amdgcn_sched_barrier(0);
  }
  asm volatile("s_waitcnt vmcnt(0) lgkmcnt(0)" ::: "memory");
  __builtin_amdgcn_s_barrier();
  __builtin_amdgcn_sched_barrier(0);
  SG_MFMA(1)
#undef SG_STAGE
#undef SG_MFMA

  const int hwv0 = hw0 + wc * 32 + lm;
#pragma unroll
  for (int mi = 0; mi < 4; ++mi) {
    int obase = wr * 64 + mi * 16 + lg * 4;
#pragma unroll
    for (int ni = 0; ni < 2; ++ni)
#pragma unroll
      for (int r = 0; r < 4; ++r) {
        int o = obase + r;
        out[((size_t)(bimg * CO + o)) * HWSZ + hwv0 + ni * 16] = acc[mi][ni][r] + b_dcn[o];
      }
  }
}

// ---------------- BN stats, two-stage ----------------
__global__ __launch_bounds__(256) void bn_stats1(const float* __restrict__ out,
                                                 float2* __restrict__ part) {
  int o = blockIdx.x, s = blockIdx.y, tid = threadIdx.x;
  const float4* p = (const float4*)(out + ((size_t)((s >> 1) * CO + o)) * HWSZ + (s & 1) * 4608);
  float sum = 0.f, sq = 0.f;
#pragma unroll
  for (int j = tid; j < 1152; j += 256) {
    float4 v = p[j];
    sum += v.x + v.y + v.z + v.w;
    sq += v.x * v.x + v.y * v.y + v.z * v.z + v.w * v.w;
  }
#pragma unroll
  for (int off = 32; off > 0; off >>= 1) {
    sum += __shfl_xor(sum, off);
    sq += __shfl_xor(sq, off);
  }
  __shared__ float rs[4], rq[4];
  if ((tid & 63) == 0) { rs[tid >> 6] = sum; rq[tid >> 6] = sq; }
  __syncthreads();
  if (tid == 0)
    part[o * 4 + s] = make_float2(rs[0] + rs[1] + rs[2] + rs[3],
                                  rq[0] + rq[1] + rq[2] + rq[3]);
}

__global__ __launch_bounds__(256) void bn_finl(const float2* __restrict__ part,
                                               const float* __restrict__ gamma,
                                               const float* __restrict__ beta,
                                               float* __restrict__ ss) {
  int o = threadIdx.x;
  float s = 0.f, sq = 0.f;
#pragma unroll
  for (int i = 0; i < 4; ++i) {
    float2 p = part[o * 4 + i];
    s += p.x; sq += p.y;
  }
  float mean = s * (1.f / (float)NPIX);
  float var = sq * (1.f / (float)NPIX) - mean * mean;
  float rstd = rsqrtf(var + 1e-5f);
  float sc = rstd * gamma[o];
  ss[o] = sc;
  ss[CO + o] = beta[o] - mean * sc;
}

// ---------------- BN apply + ReLU ----------------
__global__ void bn_apply(float* __restrict__ out, const float* __restrict__ ss) {
  int i = blockIdx.x * 256 + threadIdx.x;
  float4 v = ((float4*)out)[i];
  int o = (i / (HWSZ / 4)) & 255;
  float sc = ss[o], sh = ss[CO + o];
  v.x = fmaxf(v.x * sc + sh, 0.f);
  v.y = fmaxf(v.y * sc + sh, 0.f);
  v.z = fmaxf(v.z * sc + sh, 0.f);
  v.w = fmaxf(v.w * sc + sh, 0.f);
  ((float4*)out)[i] = v;
}

extern "C" void kernel_launch(void* const* d_in, const int* in_sizes, int n_in,
                              void* d_out, int out_size, void* d_ws, size_t ws_size,
                              hipStream_t stream) {
  const float* x = (const float*)d_in[0];
  const float* w_off = (const float*)d_in[1];
  const float* b_off = (const float*)d_in[2];
  const float* w_dcn = (const float*)d_in[3];
  const float* b_dcn = (const float*)d_in[4];
  const float* gamma = (const float*)d_in[5];
  const float* beta = (const float*)d_in[6];
  float* out = (float*)d_out;

  char* ws = (char*)d_ws;

  size_t base = 84934656;                      // S_g occupies [0, base)
  ushort_t* S_g   = (ushort_t*)(ws);
  float*    om    = (float*)(ws + base);                    // 2*27*NPIX*4 = 3,981,312
  uint_t*   offs  = (uint_t*)(ws + base + 3981312);         //   663,552
  float4*   wts   = (float4*)(ws + base + 4644864);         // 2,654,208
  ushort_t* w9r   = (ushort_t*)(ws + base + 7299072);       // 1,179,648
  ushort_t* w27r  = (ushort_t*)(ws + base + 8478720);       //   147,456
  float*    ss    = (float*)(ws + base + 8626176);          //     2,048
  float2*   bnp   = (float2*)(ws + base + 8628224);         //     8,192

  cvt_w9<<<(CO * KTOT) / 256, 256, 0, stream>>>(w_dcn, w9r);
  cvt_woff9<<<(32 * KTOT) / 256, 256, 0, stream>>>(w_off, w27r);
  off_gemm<<<dim3(NPIX / 64, 2), 512, 0, stream>>>(x, w27r, om);
  prep_kernel<<<NPIX / 128, 128, 0, stream>>>(om, b_off, offs, wts);
  sample_lds<<<dim3(4, 128), 512, 0, stream>>>(x, offs, wts, S_g);
  s_gemm<<<NPIX / 64, 512, 0, stream>>>(w9r, S_g, b_dcn, out);
  bn_stats1<<<dim3(CO, 4), 256, 0, stream>>>(out, bnp);
  bn_finl<<<1, 256, 0, stream>>>(bnp, gamma, beta, ss);
  bn_apply<<<(out_size / 4) / 256, 256, 0, stream>>>(out, ss);
}

// Round 16
// 147.182 us; speedup vs baseline: 1.9184x; 1.0835x over previous
//
#include <hip/hip_runtime.h>

// DeformConv fused pipeline, MI355X gfx950. Shapes: B=2, Ci=Co=256, H=W=96.
// R16 changes vs R15 (s_gemm 54us: 1-deep prefetch + 2 barriers/chunk exposes
// L2 latency every chunk; MfmaUtil 15%):
//  - s_gemm: 4-slot LDS ring (80KB), depth-2 prefetch, ONE barrier/chunk
//    (ring depth 4 > wave skew 1 makes barrier-2 redundant). vmcnt(6)/(4)
//    steady, 3/2 then 0 peeled tail.
//  - everything else identical to R15 (passing, 159.5us).

typedef unsigned short ushort_t;
typedef unsigned int uint_t;
typedef __attribute__((ext_vector_type(8))) short bf16x8;
typedef __attribute__((ext_vector_type(4))) float f32x4;
typedef __attribute__((ext_vector_type(2), aligned(4))) float f32x2a;

#define HH 96
#define WW 96
#define HWSZ 9216
#define CI 256
#define CO 256
#define NB 2
#define NPIX 18432
#define KTOT 2304

__device__ __forceinline__ ushort_t f2bf(float f) {
  unsigned int u = __float_as_uint(f);
  u += 0x7fffu + ((u >> 16) & 1u);
  return (ushort_t)(u >> 16);
}
__device__ __forceinline__ float u2f(uint_t u) { return __uint_as_float(u); }

__device__ __forceinline__ void gload16(const void* g, void* l) {
  __builtin_amdgcn_global_load_lds(
      (const __attribute__((address_space(1))) unsigned int*)g,
      (__attribute__((address_space(3))) unsigned int*)l, 16, 0, 0);
}

// ---------------- cvt_w9: w_dcn -> bf16 [kk>>3][m][kk&7] ----------------
__global__ void cvt_w9(const float* __restrict__ w, ushort_t* __restrict__ o) {
  int i = blockIdx.x * 256 + threadIdx.x;      // grid exact CO*KTOT
  int oo = i / KTOT;
  int kk = i - oo * KTOT;
  o[(kk >> 3) * 2048 + oo * 8 + (kk & 7)] = f2bf(w[i]);
}

// ---------------- cvt_woff9: w_off -> bf16 [kk>>3][m32][kk&7], rows>=27 zero ----
__global__ void cvt_woff9(const float* __restrict__ w, ushort_t* __restrict__ o) {
  int i = blockIdx.x * 256 + threadIdx.x;      // grid exact 32*KTOT
  int m = i / KTOT;
  int kk = i - m * KTOT;
  float v = (m < 27) ? w[m * KTOT + kk] : 0.f;
  o[(kk >> 3) * 256 + m * 8 + (kk & 7)] = f2bf(v);
}

// ---------------- off_gemm: om_part[part][27][NPIX], K-split halves ----------------
__global__ __launch_bounds__(512, 2) void off_gemm(
    const float* __restrict__ x, const ushort_t* __restrict__ w27r,
    float* __restrict__ om_part) {
  __shared__ __align__(16) ushort_t A27[2][2048];
  __shared__ __align__(16) ushort_t B64[4096];
  __shared__ uint2 tbl[9][64];                 // {abs idx (0 if invalid), mask}

  const int tid = threadIdx.x;
  const int lane = tid & 63, wid = tid >> 6;
  const int p0 = blockIdx.x * 64;
  const int part = blockIdx.y;                 // K half
  const int bimg = p0 / HWSZ;
  const int hw0 = p0 - bimg * HWSZ;
  const float* xb = x + (size_t)bimg * CI * HWSZ;

  for (int e = tid; e < 576; e += 512) {
    int k = e >> 6, px = e & 63;
    int hw = hw0 + px, h = hw / WW, w_ = hw - h * WW;
    int dy = k / 3 - 1, dx = k % 3 - 1;
    bool ok = (h + dy >= 0) && (h + dy < HH) && (w_ + dx >= 0) && (w_ + dx < WW);
    tbl[k][px] = make_uint2(ok ? (uint_t)(hw + dy * WW + dx) : 0u,
                            ok ? 0x3f800000u : 0u);
  }

  const int lg = lane >> 4, lm = lane & 15;
  const int wr = wid >> 2, wc = wid & 3;
  f32x4 acc = (f32x4){0.f, 0.f, 0.f, 0.f};

  int cj[8], kj[8];
#pragma unroll
  for (int j = 0; j < 8; ++j) {
    int kk = part * 1152 + wid * 8 + j;
    cj[j] = kk / 9;
    kj[j] = kk - 9 * cj[j];
  }
  __syncthreads();

  float rv0[8], rm0[8], rv1[8], rm1[8];
  const int k0 = part * 18;

#define OG_RAW(RV, RM)                                                        \
  { _Pragma("unroll") for (int j = 0; j < 8; ++j) {                           \
      uint2 e_ = tbl[kj[j]][lane];                                            \
      RV[j] = xb[cj[j] * HWSZ + (int)e_.x];                                   \
      RM[j] = u2f(e_.y);                                                      \
      kj[j] += 1; cj[j] += 7;                                                 \
      if (kj[j] == 9) { kj[j] = 0; cj[j] += 1; } } }
#define OG_GA(CH, BUF)                                                        \
  gload16(w27r + (size_t)(CH) * 2048 + (tid & 255) * 8, &A27[BUF][(wid & 3) * 512]);
#define OG_STEP(CUR, RVC, RMC, RVN, RMN, KO)                                  \
  {                                                                           \
    if ((KO) < 17) {                                                          \
      OG_RAW(RVN, RMN)                                                        \
      OG_GA(k0 + (KO) + 1, (CUR) ^ 1)                                         \
      asm volatile("s_waitcnt vmcnt(10)" ::: "memory");                       \
    } else {                                                                  \
      asm volatile("s_waitcnt vmcnt(1)" ::: "memory");                        \
    }                                                                         \
    __builtin_amdgcn_sched_barrier(0);                                        \
    {                                                                         \
      ushort_t sv_[8] __attribute__((aligned(16)));                           \
      _Pragma("unroll") for (int j = 0; j < 8; ++j)                           \
        sv_[j] = f2bf(RVC[j] * RMC[j]);                                       \
      *(uint4*)&B64[tid * 8] = *(const uint4*)sv_;                            \
    }                                                                         \
    if ((KO) < 17) asm volatile("s_waitcnt vmcnt(9) lgkmcnt(0)" ::: "memory"); \
    else           asm volatile("s_waitcnt vmcnt(0) lgkmcnt(0)" ::: "memory"); \
    __builtin_amdgcn_s_barrier();                                             \
    __builtin_amdgcn_sched_barrier(0);                                        \
    _Pragma("unroll") for (int s = 0; s < 2; ++s) {                           \
      bf16x8 af = *(const bf16x8*)&A27[CUR][((s * 4 + lg) * 32 + wr * 16 + lm) * 8]; \
      bf16x8 bfv = *(const bf16x8*)&B64[((s * 4 + lg) * 64 + wc * 16 + lm) * 8];     \
      acc = __builtin_amdgcn_mfma_f32_16x16x32_bf16(af, bfv, acc, 0, 0, 0);   \
    }                                                                         \
    asm volatile("s_waitcnt lgkmcnt(0)" ::: "memory");                        \
    __builtin_amdgcn_s_barrier();                                             \
    __builtin_amdgcn_sched_barrier(0);                                        \
  }

  OG_RAW(rv0, rm0)
  OG_GA(k0, 0)
  for (int ko2 = 0; ko2 < 9; ++ko2) {
    const int ko = ko2 * 2;
    OG_STEP(0, rv0, rm0, rv1, rm1, ko)
    OG_STEP(1, rv1, rm1, rv0, rm0, ko + 1)
  }
#undef OG_RAW
#undef OG_GA
#undef OG_STEP

  int row = wr * 16 + lg * 4;
  int col = p0 + wc * 16 + lm;
#pragma unroll
  for (int r = 0; r < 4; ++r)
    if (row + r < 27)
      om_part[((size_t)(part * 27 + row + r)) * NPIX + col] = acc[r];
}

// ---------------- prep: sum om halves -> row-pair offsets + folded weights ----------------
__global__ void prep_kernel(const float* __restrict__ om_part, const float* __restrict__ b_off,
                            uint_t* __restrict__ offs, float4* __restrict__ wts) {
  int n = blockIdx.x * 128 + threadIdx.x;      // grid 144 x 128
  float omv[27];
#pragma unroll
  for (int ch = 0; ch < 27; ++ch)
    omv[ch] = b_off[ch] + om_part[(size_t)ch * NPIX + n] +
              om_part[((size_t)(27 + ch)) * NPIX + n];
  int hw = n % HWSZ;
  int h = hw / WW, w = hw - h * WW;
#pragma unroll
  for (int k = 0; k < 9; ++k) {
    float dy = omv[2 * k], dx = omv[2 * k + 1];
    float mk = 1.f / (1.f + __expf(-omv[18 + k]));
    float py = dy + (float)(h - 1 + k / 3);
    float px = dx + (float)(w - 1 + k % 3);
    float y0f = floorf(py), x0f = floorf(px);
    int y0 = (int)y0f, x0 = (int)x0f;
    float wy1 = py - y0f, wx1 = px - x0f;
    float wy0 = 1.f - wy1, wx0 = 1.f - wx1;
    float vy0 = (y0 >= 0 && y0 <= HH - 1) ? 1.f : 0.f;
    float vy1 = (y0 + 1 >= 0 && y0 + 1 <= HH - 1) ? 1.f : 0.f;
    int yc0 = min(max(y0, 0), HH - 1), yc1 = min(max(y0 + 1, 0), HH - 1);
    int xa = min(max(x0, 0), WW - 2);
    float a_, b_;
    if (x0 >= 0 && x0 <= WW - 2)      { a_ = wx0; b_ = wx1; }
    else if (x0 == -1)                { a_ = wx1; b_ = 0.f; }
    else if (x0 == WW - 1)            { a_ = 0.f; b_ = wx0; }
    else                              { a_ = 0.f; b_ = 0.f; }
    float s0 = mk * vy0 * wy0, s1 = mk * vy1 * wy1;
    offs[(size_t)k * NPIX + n] = (uint_t)(yc0 * WW + xa) | ((uint_t)(yc1 * WW + xa) << 16);
    wts[(size_t)k * NPIX + n] = make_float4(a_ * s0, b_ * s0, a_ * s1, b_ * s1);
  }
}

// ---------------- sample_lds: S_g[kk>>3][n][kk&7] bf16 ----------------
// Grid (4, 128): blockIdx.x = img*2+half, blockIdx.y = c-pair. Block stages
// both channel images (72 KB LDS), gathers from LDS, 9 px/thread.
__global__ __launch_bounds__(512, 2) void sample_lds(
    const float* __restrict__ x, const uint_t* __restrict__ offs,
    const float4* __restrict__ wts, ushort_t* __restrict__ S_g) {
  __shared__ float xl[2][HWSZ];                // 73,728 B
  const int tid = threadIdx.x;
  const int wid = tid >> 6;
  const int img = blockIdx.x >> 1;
  const int half = blockIdx.x & 1;
  const int cp = blockIdx.y;                   // 0..127
  const int n0 = img * HWSZ + half * 4608;

  // ---- stage 2 channel images: 18432 floats = 9 passes x 512 thr x 16B ----
  {
    const float* src = x + ((size_t)(img * CI + 2 * cp)) * HWSZ;
    float* dst = &xl[0][0];
#pragma unroll
    for (int i = 0; i < 9; ++i)
      gload16(src + i * 2048 + tid * 4, dst + i * 2048 + wid * 256);
  }
  __syncthreads();

  // ---- 9 pixels per thread ----
  for (int j = 0; j < 9; ++j) {
    const int n = n0 + tid + j * 512;
    uint_t ofr[9]; float4 wtr[9];
#pragma unroll
    for (int k = 0; k < 9; ++k) {
      ofr[k] = offs[(size_t)k * NPIX + n];
      wtr[k] = wts[(size_t)k * NPIX + n];
    }
    uint_t pkw[9];
#pragma unroll
    for (int i = 0; i < 9; ++i) pkw[i] = 0u;
#pragma unroll
    for (int k = 0; k < 9; ++k) {
      const int o0 = (int)(ofr[k] & 0xffffu);
      const int o1 = (int)(ofr[k] >> 16);
      float a0x = xl[0][o0], a0y = xl[0][o0 + 1];
      float b0x = xl[0][o1], b0y = xl[0][o1 + 1];
      float a1x = xl[1][o0], a1y = xl[1][o0 + 1];
      float b1x = xl[1][o1], b1y = xl[1][o1 + 1];
      float v0 = wtr[k].x * a0x + wtr[k].y * a0y + wtr[k].z * b0x + wtr[k].w * b0y;
      float v1 = wtr[k].x * a1x + wtr[k].y * a1y + wtr[k].z * b1x + wtr[k].w * b1y;
      const int q0 = k, q1 = 9 + k;
      pkw[q0 >> 1] |= ((uint_t)f2bf(v0)) << ((q0 & 1) * 16);
      pkw[q1 >> 1] |= ((uint_t)f2bf(v1)) << ((q1 & 1) * 16);
    }
#pragma unroll
    for (int jj = 0; jj < 9; ++jj) {
      const int kk = cp * 18 + 2 * jj;
      *(uint_t*)&S_g[((size_t)(kk >> 3) * NPIX + n) * 8 + (kk & 7)] = pkw[jj];
    }
  }
}

// ---------------- s_gemm: out = W9 * S + b_dcn ----------------
// BM=256, BN=64, BK=32, 72 chunks, grid 288, 512 thr / 8 waves, wave 64x32.
// 4-slot LDS ring (80 KB), depth-2 prefetch, ONE barrier per chunk.
__global__ __launch_bounds__(512, 2) void s_gemm(
    const ushort_t* __restrict__ w9r, const ushort_t* __restrict__ S_g,
    const float* __restrict__ b_dcn, float* __restrict__ out) {
  __shared__ __align__(16) ushort_t A[4][8192];   // 64 KB
  __shared__ __align__(16) ushort_t S[4][2048];   // 16 KB

  const int tid = threadIdx.x;
  const int lane = tid & 63, wid = tid >> 6;
  const int p0 = blockIdx.x * 64;
  const int bimg = p0 / HWSZ;
  const int hw0 = p0 - bimg * HWSZ;
  const int lg = lane >> 4, lm = lane & 15;
  const int wr = wid >> 1, wc = wid & 1;

  f32x4 acc[4][2];
#pragma unroll
  for (int i = 0; i < 4; ++i)
#pragma unroll
    for (int j = 0; j < 2; ++j) acc[i][j] = (f32x4){0.f, 0.f, 0.f, 0.f};

#define SG_STAGE(CH, BUF)                                                     \
  {                                                                           \
    gload16(w9r + (size_t)(CH) * 8192 + tid * 8, &A[BUF][wid * 512]);         \
    gload16(w9r + (size_t)(CH) * 8192 + 4096 + tid * 8, &A[BUF][4096 + wid * 512]); \
    if (wid < 4)                                                              \
      gload16(S_g + ((size_t)((CH) * 4 + wid) * NPIX + p0 + lane) * 8,        \
              &S[BUF][wid * 512]);                                            \
  }
#define SG_MFMA(BUF)                                                          \
  {                                                                           \
    bf16x8 bfr0 = *(const bf16x8*)&S[BUF][(lg * 64 + wc * 32 + lm) * 8];      \
    bf16x8 bfr1 = *(const bf16x8*)&S[BUF][(lg * 64 + wc * 32 + 16 + lm) * 8]; \
    _Pragma("unroll") for (int mi = 0; mi < 4; ++mi) {                        \
      bf16x8 af = *(const bf16x8*)&A[BUF][(lg * 256 + wr * 64 + mi * 16 + lm) * 8]; \
      acc[mi][0] = __builtin_amdgcn_mfma_f32_16x16x32_bf16(af, bfr0, acc[mi][0], 0, 0, 0); \
      acc[mi][1] = __builtin_amdgcn_mfma_f32_16x16x32_bf16(af, bfr1, acc[mi][1], 0, 0, 0); \
    }                                                                         \
  }

  SG_STAGE(0, 0)
  SG_STAGE(1, 1)
  for (int ko = 0; ko < 70; ++ko) {
    SG_STAGE(ko + 2, (ko + 2) & 3)
    if (wid < 4) { asm volatile("s_waitcnt vmcnt(6)" ::: "memory"); }
    else         { asm volatile("s_waitcnt vmcnt(4)" ::: "memory"); }
    __builtin_amdgcn_s_barrier();
    __builtin_amdgcn_sched_barrier(0);
    SG_MFMA(ko & 3)
  }
  // ko = 70: only chunk 71's stage outstanding
  if (wid < 4) { asm volatile("s_waitcnt vmcnt(3)" ::: "memory"); }
  else         { asm volatile("s_waitcnt vmcnt(2)" ::: "memory"); }
  __builtin_amdgcn_s_barrier();
  __builtin_amdgcn_sched_barrier(0);
  SG_MFMA(2)
  // ko = 71: drain
  asm volatile("s_waitcnt vmcnt(0)" ::: "memory");
  __builtin_amdgcn_s_barrier();
  __builtin_amdgcn_sched_barrier(0);
  SG_MFMA(3)
#undef SG_STAGE
#undef SG_MFMA

  const int hwv0 = hw0 + wc * 32 + lm;
#pragma unroll
  for (int mi = 0; mi < 4; ++mi) {
    int obase = wr * 64 + mi * 16 + lg * 4;
#pragma unroll
    for (int ni = 0; ni < 2; ++ni)
#pragma unroll
      for (int r = 0; r < 4; ++r) {
        int o = obase + r;
        out[((size_t)(bimg * CO + o)) * HWSZ + hwv0 + ni * 16] = acc[mi][ni][r] + b_dcn[o];
      }
  }
}

// ---------------- BN stats, two-stage ----------------
__global__ __launch_bounds__(256) void bn_stats1(const float* __restrict__ out,
                                                 float2* __restrict__ part) {
  int o = blockIdx.x, s = blockIdx.y, tid = threadIdx.x;
  const float4* p = (const float4*)(out + ((size_t)((s >> 1) * CO + o)) * HWSZ + (s & 1) * 4608);
  float sum = 0.f, sq = 0.f;
#pragma unroll
  for (int j = tid; j < 1152; j += 256) {
    float4 v = p[j];
    sum += v.x + v.y + v.z + v.w;
    sq += v.x * v.x + v.y * v.y + v.z * v.z + v.w * v.w;
  }
#pragma unroll
  for (int off = 32; off > 0; off >>= 1) {
    sum += __shfl_xor(sum, off);
    sq += __shfl_xor(sq, off);
  }
  __shared__ float rs[4], rq[4];
  if ((tid & 63) == 0) { rs[tid >> 6] = sum; rq[tid >> 6] = sq; }
  __syncthreads();
  if (tid == 0)
    part[o * 4 + s] = make_float2(rs[0] + rs[1] + rs[2] + rs[3],
                                  rq[0] + rq[1] + rq[2] + rq[3]);
}

__global__ __launch_bounds__(256) void bn_finl(const float2* __restrict__ part,
                                               const float* __restrict__ gamma,
                                               const float* __restrict__ beta,
                                               float* __restrict__ ss) {
  int o = threadIdx.x;
  float s = 0.f, sq = 0.f;
#pragma unroll
  for (int i = 0; i < 4; ++i) {
    float2 p = part[o * 4 + i];
    s += p.x; sq += p.y;
  }
  float mean = s * (1.f / (float)NPIX);
  float var = sq * (1.f / (float)NPIX) - mean * mean;
  float rstd = rsqrtf(var + 1e-5f);
  float sc = rstd * gamma[o];
  ss[o] = sc;
  ss[CO + o] = beta[o] - mean * sc;
}

// ---------------- BN apply + ReLU ----------------
__global__ void bn_apply(float* __restrict__ out, const float* __restrict__ ss) {
  int i = blockIdx.x * 256 + threadIdx.x;
  float4 v = ((float4*)out)[i];
  int o = (i / (HWSZ / 4)) & 255;
  float sc = ss[o], sh = ss[CO + o];
  v.x = fmaxf(v.x * sc + sh, 0.f);
  v.y = fmaxf(v.y * sc + sh, 0.f);
  v.z = fmaxf(v.z * sc + sh, 0.f);
  v.w = fmaxf(v.w * sc + sh, 0.f);
  ((float4*)out)[i] = v;
}

extern "C" void kernel_launch(void* const* d_in, const int* in_sizes, int n_in,
                              void* d_out, int out_size, void* d_ws, size_t ws_size,
                              hipStream_t stream) {
  const float* x = (const float*)d_in[0];
  const float* w_off = (const float*)d_in[1];
  const float* b_off = (const float*)d_in[2];
  const float* w_dcn = (const float*)d_in[3];
  const float* b_dcn = (const float*)d_in[4];
  const float* gamma = (const float*)d_in[5];
  const float* beta = (const float*)d_in[6];
  float* out = (float*)d_out;

  char* ws = (char*)d_ws;

  size_t base = 84934656;                      // S_g occupies [0, base)
  ushort_t* S_g   = (ushort_t*)(ws);
  float*    om    = (float*)(ws + base);                    // 2*27*NPIX*4 = 3,981,312
  uint_t*   offs  = (uint_t*)(ws + base + 3981312);         //   663,552
  float4*   wts   = (float4*)(ws + base + 4644864);         // 2,654,208
  ushort_t* w9r   = (ushort_t*)(ws + base + 7299072);       // 1,179,648
  ushort_t* w27r  = (ushort_t*)(ws + base + 8478720);       //   147,456
  float*    ss    = (float*)(ws + base + 8626176);          //     2,048
  float2*   bnp   = (float2*)(ws + base + 8628224);         //     8,192

  cvt_w9<<<(CO * KTOT) / 256, 256, 0, stream>>>(w_dcn, w9r);
  cvt_woff9<<<(32 * KTOT) / 256, 256, 0, stream>>>(w_off, w27r);
  off_gemm<<<dim3(NPIX / 64, 2), 512, 0, stream>>>(x, w27r, om);
  prep_kernel<<<NPIX / 128, 128, 0, stream>>>(om, b_off, offs, wts);
  sample_lds<<<dim3(4, 128), 512, 0, stream>>>(x, offs, wts, S_g);
  s_gemm<<<NPIX / 64, 512, 0, stream>>>(w9r, S_g, b_dcn, out);
  bn_stats1<<<dim3(CO, 4), 256, 0, stream>>>(out, bnp);
  bn_finl<<<1, 256, 0, stream>>>(bnp, gamma, beta, ss);
  bn_apply<<<(out_size / 4) / 256, 256, 0, stream>>>(out, ss);
}